// Round 3
// baseline (461.067 us; speedup 1.0000x reference)
//
#include <hip/hip_runtime.h>
#include <cstdint>

#define N 8192
#define FIN 256
#define FOUT 128
#define ALPHA 0.2f
#define JP 4                  // j-split
#define JSL (N / JP)          // 2048 j per block
#define TJ 64                 // j-tile
#define NTILE (JSL / TJ)      // 32 tiles
#define RB 32                 // rows per block
#define PACKB (N * N / 32 / 256)   // 8192 pack blocks in k_prep

typedef unsigned short u16;
typedef unsigned char u8;
typedef __attribute__((ext_vector_type(8))) short short8;
typedef __attribute__((ext_vector_type(4))) float floatx4;

__device__ __forceinline__ u16 bf16_rne(float f) {
  uint32_t u = __float_as_uint(f);
  u += 0x7fff + ((u >> 16) & 1);
  return (u16)(u >> 16);
}

// async global->LDS DMA, 16 B per lane, whole wave. LDS dest = uniform base
// + lane*16 (m104: wave-uniform base, lane-contiguous — layout must match).
__device__ __forceinline__ void gl_lds16(const void* g, void* l) {
  __builtin_amdgcn_global_load_lds(
      (const __attribute__((address_space(1))) void*)g,
      (__attribute__((address_space(3))) void*)l, 16, 0, 0);
}

// ---------------------------------------------------------------------------
// Kernel 1 (fused): blocks [0, PACKB) pack adj -> bitmask (268 MB stream at
// full HBM BW); blocks [PACKB, PACKB+1024) do h = x@W, hT3 bf16 tiling,
// src/dst vectors. Fusing saves one launch boundary; bodies unchanged.
// ---------------------------------------------------------------------------
__global__ __launch_bounds__(256) void k_prep(const int* __restrict__ adj,
                                              uint32_t* __restrict__ bmo,
                                              const float* __restrict__ x,
                                              const float* __restrict__ W,
                                              const float* __restrict__ a,
                                              u16* __restrict__ hT3,
                                              float* __restrict__ srcv,
                                              float* __restrict__ dstv) {
  __shared__ float xs[8 * FIN];                     // 8 KB (proj blocks only)
  __shared__ float partS[4][4], partD[4][4];
  const int bid = blockIdx.x;
  const int t = threadIdx.x;

  if (bid < PACKB) {
    // ---- pack: thread packs 32 consecutive ints into one u32 bit-mask ----
    const int tt = bid * 256 + t;                  // 0 .. N*N/32-1
    const int4* p = (const int4*)adj + (size_t)tt * 8;
    int4 v[8];
    #pragma unroll
    for (int k = 0; k < 8; ++k) v[k] = p[k];
    uint32_t mk = 0;
    #pragma unroll
    for (int k = 0; k < 8; ++k) {
      mk |= (uint32_t)(v[k].x > 0) << (4 * k + 0);
      mk |= (uint32_t)(v[k].y > 0) << (4 * k + 1);
      mk |= (uint32_t)(v[k].z > 0) << (4 * k + 2);
      mk |= (uint32_t)(v[k].w > 0) << (4 * k + 3);
    }
    bmo[tt] = mk;
    return;
  }

  // ---- proj: unchanged body ----
  const int R0 = (bid - PACKB) * 8;

  const float4* xv = (const float4*)(x + (size_t)R0 * FIN);
  float4* xsv = (float4*)xs;
  xsv[t] = xv[t];
  xsv[t + 256] = xv[t + 256];
  __syncthreads();

  const int c  = t & 127;
  const int rg = (t >> 7) * 4;

  float acc[4] = {0.f, 0.f, 0.f, 0.f};
  float wa[4], wb[4];
  #pragma unroll
  for (int j = 0; j < 4; ++j) wa[j] = W[j * FOUT + c];
  #pragma unroll
  for (int j = 0; j < 4; ++j) wb[j] = W[(4 + j) * FOUT + c];

  for (int k4 = 0; k4 < FIN / 4; ++k4) {
    float wc[4];
    #pragma unroll
    for (int j = 0; j < 4; ++j) { wc[j] = wa[j]; wa[j] = wb[j]; }
    const int kn = (k4 + 2 < FIN / 4) ? k4 + 2 : k4;
    #pragma unroll
    for (int j = 0; j < 4; ++j) wb[j] = W[(kn * 4 + j) * FOUT + c];
    #pragma unroll
    for (int i = 0; i < 4; ++i) {
      const float4 xq = *(const float4*)&xs[(rg + i) * FIN + k4 * 4];
      acc[i] += xq.x * wc[0] + xq.y * wc[1] + xq.z * wc[2] + xq.w * wc[3];
    }
  }

  {
    const int j = R0 + rg;
    const int jb = j >> 5, q = (j >> 3) & 3, jj = j & 7;
    const int m = c & 15, nt = c >> 4;
    union { u16 u[4]; uint2 v; } pk;
    #pragma unroll
    for (int i = 0; i < 4; ++i) pk.u[i] = bf16_rne(acc[i]);
    *(uint2*)(hT3 + (size_t)(((jb * 8 + nt) * 64) + (m * 4 + q)) * 8 + jj) = pk.v;
  }

  const float a1 = a[c], a2 = a[FOUT + c];
  float s4[4], d4[4];
  #pragma unroll
  for (int i = 0; i < 4; ++i) { s4[i] = acc[i] * a1; d4[i] = acc[i] * a2; }
  #pragma unroll
  for (int off = 32; off > 0; off >>= 1) {
    #pragma unroll
    for (int i = 0; i < 4; ++i) {
      s4[i] += __shfl_down(s4[i], off);
      d4[i] += __shfl_down(d4[i], off);
    }
  }
  const int wv = t >> 6, lane = t & 63;
  if (lane == 0) {
    #pragma unroll
    for (int i = 0; i < 4; ++i) { partS[wv][i] = s4[i]; partD[wv][i] = d4[i]; }
  }
  __syncthreads();
  if (t < 16) {
    const int i = t & 3, rg2 = (t >> 2) & 1, which = t >> 3;
    if (which == 0) srcv[R0 + rg2 * 4 + i] = partS[rg2*2][i] + partS[rg2*2+1][i];
    else            dstv[R0 + rg2 * 4 + i] = partD[rg2*2][i] + partD[rg2*2+1][i];
  }
}

// ---------------------------------------------------------------------------
// Kernel 2: fused GAT, round-3 restructure — A-fragments computed IN
// REGISTERS (no S tile, no ds_write, no second barrier). Lane (q,m) of wave
// (rh,ch) computes exactly its MFMA A-frag: p(row=R0+rh*16+m,
// col=tile*64+q*8+e) from srcv scalar + 2 broadcast float4 of dstv + 2
// bitmask bytes (ch=0/1 waves duplicate the cheap exp work). One barrier per
// tile (hS buffer protocol): vmcnt(4) retires exactly the 4 DMA chunks;
// dst/mask prefetch stays in flight (statically 2x-unrolled ping-pong, no
// tail register copy -> compiler's counted wait lands in next exp phase).
// ---------------------------------------------------------------------------
__global__ __launch_bounds__(256, 4) void k_gat(const u8* __restrict__ bmk,
                                                const u16* __restrict__ hT3,
                                                const float* __restrict__ srcv,
                                                const float* __restrict__ dstv,
                                                float* __restrict__ P,
                                                float* __restrict__ lp) {
  __shared__ u16 hS[2][8192];      // 2 x 16 KB staged hT tiles
  const int t = threadIdx.x;
  const int wv = t >> 6, lane = t & 63;
  const int q = lane >> 4, m = lane & 15;
  const int bm = blockIdx.x & 255;
  const int jp = blockIdx.x >> 8;
  const int R0 = bm * RB;
  const int j0 = jp * JSL;

  // MFMA mapping: wave -> (row-half rh, col-half ch)
  const int rh = wv & 1, ch = wv >> 1;
  const int Lq = m * 4 + q;                      // hS lane index

  const int row = R0 + rh * 16 + m;              // this lane's A-frag row
  const float srcr = srcv[row];
  const float* dstp = dstv + j0 + q * 8;         // + tile*64 (+32 for a1)
  const u8*    bmp  = bmk + (size_t)row * (N >> 3) + (j0 >> 3) + q;

  floatx4 acc[4];
  #pragma unroll
  for (int nt = 0; nt < 4; ++nt) acc[nt] = (floatx4){0.f, 0.f, 0.f, 0.f};
  float lsum = 0.f;

  // DMA one tile (16 KB = 16 chunks of 1 KB); wave wv stages chunks wv*4..+4
  const size_t jb00 = (size_t)(j0 >> 5);
  #define STAGE(I, BUF)                                                        \
  {                                                                            \
    _Pragma("unroll")                                                          \
    for (int cc = 0; cc < 4; ++cc) {                                           \
      const int kc = wv * 4 + cc;               /* 0..15 */                    \
      const int jbl = kc >> 3, nt_ = kc & 7;                                   \
      const u16* src = hT3 + ((jb00 + (size_t)(I) * 2 + jbl) * 8 + nt_) * 512  \
                       + (size_t)lane * 8;                                     \
      gl_lds16(src, &hS[BUF][kc * 512]);                                       \
    }                                                                          \
  }

  // One stage: barrier(tile i ready) -> DMA i+1 -> prefetch dst/mask i+1 ->
  // exp into A-frags (regs) -> MFMA from hS[BUF].
  #define GBODY(i, BUF, dA, dB, mA, mB, dAn, dBn, mAn, mBn)                    \
  {                                                                            \
    asm volatile("s_waitcnt vmcnt(4) lgkmcnt(0)" ::: "memory");                \
    __builtin_amdgcn_s_barrier();                                              \
    __builtin_amdgcn_sched_barrier(0);                                         \
    if ((i) + 1 < NTILE) STAGE((i) + 1, (BUF) ^ 1)                             \
    __builtin_amdgcn_sched_barrier(0);   /* pin: DMA before prefetch loads */  \
    const int nx_ = ((i) + 1 < NTILE) ? (i) + 1 : (i);                         \
    dAn = *(const float4*)(dstp + nx_ * TJ);                                   \
    dBn = *(const float4*)(dstp + nx_ * TJ + 32);                              \
    mAn = bmp[nx_ * 8];                                                        \
    mBn = bmp[nx_ * 8 + 4];                                                    \
    union { u16 u[8]; short8 s; } A0_, A1_;                                    \
    {                                                                          \
      const float dfa[8] = {dA.x, dA.y, dA.z, dA.w, dA.x, dA.y, dA.z, dA.w};   \
      (void)dfa; /* placeholder removed below */                               \
    }                                                                          \
    {                                                                          \
      const float f0[4] = {dA.x, dA.y, dA.z, dA.w};                            \
      _Pragma("unroll")                                                        \
      for (int e = 0; e < 4; ++e) {                                            \
        float v = srcr + f0[e];                                                \
        v = fmaxf(v, ALPHA * v);                                               \
        const float p = ((mA >> e) & 1) ? __expf(v) : 0.f;                     \
        lsum += p; A0_.u[e] = bf16_rne(p);                                     \
      }                                                                        \
      const float f1[4] = {dA.w, dA.w, dA.w, dA.w};                            \
      (void)f1;                                                                \
    }                                                                          \
    GBODY_UNUSED                                                               \
  }

  #undef GBODY
  #undef GBODY_UNUSED
  // (macro above scrapped for clarity — explicit helper lambda instead)

  // exp 8 cols from a float4 pair is awkward in a macro; use a lambda.
  auto mk_frag = [&](const float4 dlo, const float4 dhi, const u8 mk,
                     float& ls) -> short8 {
    union { u16 u[8]; short8 s; } A_;
    const float df[8] = {dlo.x, dlo.y, dlo.z, dlo.w, dhi.x, dhi.y, dhi.z, dhi.w};
    #pragma unroll
    for (int e = 0; e < 8; ++e) {
      float v = srcr + df[e];
      v = fmaxf(v, ALPHA * v);
      const float p = ((mk >> e) & 1) ? __expf(v) : 0.f;
      ls += p;
      A_.u[e] = bf16_rne(p);
    }
    return A_.s;
  };

  #define GSTAGE(i, BUF, dA0, dA1, dB0, dB1, mA, mB,                           \
                        dC0, dC1, dD0, dD1, mC, mD)                            \
  {                                                                            \
    asm volatile("s_waitcnt vmcnt(4) lgkmcnt(0)" ::: "memory");                \
    __builtin_amdgcn_s_barrier();                                              \
    __builtin_amdgcn_sched_barrier(0);                                         \
    if ((i) + 1 < NTILE) STAGE((i) + 1, (BUF) ^ 1)                             \
    __builtin_amdgcn_sched_barrier(0);   /* pin: DMA before prefetch loads */  \
    const int nx_ = ((i) + 1 < NTILE) ? (i) + 1 : (i);                         \
    dC0 = *(const float4*)(dstp + nx_ * TJ);                                   \
    dC1 = *(const float4*)(dstp + nx_ * TJ + 4);                               \
    dD0 = *(const float4*)(dstp + nx_ * TJ + 32);                              \
    dD1 = *(const float4*)(dstp + nx_ * TJ + 36);                              \
    mC = bmp[nx_ * 8];                                                         \
    mD = bmp[nx_ * 8 + 4];                                                     \
    const short8 a0 = mk_frag(dA0, dA1, mA, lsum);                             \
    const short8 a1 = mk_frag(dB0, dB1, mB, lsum);                             \
    _Pragma("unroll")                                                          \
    for (int nt = 0; nt < 4; ++nt) {                                           \
      const short8 b0 = *(const short8*)&hS[BUF][(0 * 8 + ch * 4 + nt) * 512 + Lq * 8]; \
      const short8 b1 = *(const short8*)&hS[BUF][(1 * 8 + ch * 4 + nt) * 512 + Lq * 8]; \
      acc[nt] = __builtin_amdgcn_mfma_f32_16x16x32_bf16(a0, b0, acc[nt], 0, 0, 0); \
      acc[nt] = __builtin_amdgcn_mfma_f32_16x16x32_bf16(a1, b1, acc[nt], 0, 0, 0); \
    }                                                                          \
  }

  // prologue: stage tile 0 into buf 0; prefetch tile-0 dst/mask into regs
  STAGE(0, 0)
  __builtin_amdgcn_sched_barrier(0);   // DMAs strictly oldest in VMEM queue
  float4 pA0 = *(const float4*)(dstp);
  float4 pA1 = *(const float4*)(dstp + 4);
  float4 pB0 = *(const float4*)(dstp + 32);
  float4 pB1 = *(const float4*)(dstp + 36);
  u8 pmA = bmp[0], pmB = bmp[4];
  float4 qA0, qA1, qB0, qB1; u8 qmA, qmB;

  for (int i = 0; i < NTILE; i += 2) {
    GSTAGE(i,     0, pA0, pA1, pB0, pB1, pmA, pmB,
                     qA0, qA1, qB0, qB1, qmA, qmB)
    GSTAGE(i + 1, 1, qA0, qA1, qB0, qB1, qmA, qmB,
                     pA0, pA1, pB0, pB1, pmA, pmB)
  }
  #undef GSTAGE
  #undef STAGE

  // row-sum: lanes {m, m+16, m+32, m+48} (q=0..3) hold disjoint col-chunks
  // of the same row; butterfly over q. ch=0 waves write (ch=1 duplicates).
  lsum += __shfl_xor(lsum, 16);
  lsum += __shfl_xor(lsum, 32);
  if (ch == 0 && q == 0) lp[(size_t)jp * N + row] = lsum;

  // partial store (C/D layout: row = q*4+ri, col = nt*16+m)
  float* Pp = P + ((size_t)jp * N + R0 + rh * 16) * FOUT + ch * 64;
  #pragma unroll
  for (int nt = 0; nt < 4; ++nt)
    #pragma unroll
    for (int ri = 0; ri < 4; ++ri)
      Pp[(size_t)(q * 4 + ri) * FOUT + nt * 16 + m] = acc[nt][ri];
}

// ---------------------------------------------------------------------------
// Kernel 3: sum JP partials, normalize by row-sum. ~36 MB traffic.
// ---------------------------------------------------------------------------
__global__ __launch_bounds__(256) void k_norm(const float* __restrict__ P,
                                              const float* __restrict__ lp,
                                              float* __restrict__ out) {
  const int idx = blockIdx.x * 256 + threadIdx.x;   // 0 .. N*FOUT/4-1
  const int rr = idx >> 5;
  const int c4 = (idx & 31) * 4;
  float l = 0.f;
  #pragma unroll
  for (int j = 0; j < JP; ++j) l += lp[j * N + rr];
  const float inv = 1.0f / l;
  float4 s = {0.f, 0.f, 0.f, 0.f};
  #pragma unroll
  for (int j = 0; j < JP; ++j) {
    const float4 p = *(const float4*)(P + ((size_t)j * N + rr) * FOUT + c4);
    s.x += p.x; s.y += p.y; s.z += p.z; s.w += p.w;
  }
  s.x *= inv; s.y *= inv; s.z *= inv; s.w *= inv;
  *(float4*)(out + (size_t)rr * FOUT + c4) = s;
}

extern "C" void kernel_launch(void* const* d_in, const int* in_sizes, int n_in,
                              void* d_out, int out_size, void* d_ws, size_t ws_size,
                              hipStream_t stream) {
  const float* x   = (const float*)d_in[0];
  const int*   adj = (const int*)d_in[1];
  const float* W   = (const float*)d_in[2];
  const float* a   = (const float*)d_in[3];
  float* out = (float*)d_out;

  char* ws = (char*)d_ws;
  u16*   hT3  = (u16*)ws;     ws += (size_t)FOUT * N * sizeof(u16);            // 2 MB
  float* srcv = (float*)ws;   ws += (size_t)N * sizeof(float);
  float* dstv = (float*)ws;   ws += (size_t)N * sizeof(float);
  float* P    = (float*)ws;   ws += (size_t)JP * N * FOUT * sizeof(float);     // 16 MB
  float* lp   = (float*)ws;   ws += (size_t)JP * N * sizeof(float);
  u8*    bmk  = (u8*)ws;      ws += (size_t)N * (N / 8);                       // 8 MB

  k_prep<<<PACKB + N / 8, 256, 0, stream>>>(adj, (uint32_t*)bmk, x, W, a,
                                            hT3, srcv, dstv);
  k_gat <<<256 * JP, 256, 0, stream>>>(bmk, hT3, srcv, dstv, P, lp);
  k_norm<<<(N * FOUT / 4) / 256, 256, 0, stream>>>(P, lp, out);
}